// Round 8
// baseline (288.471 us; speedup 1.0000x reference)
//
#include <hip/hip_runtime.h>
#include <math.h>

typedef unsigned int   uint;
typedef unsigned short ushort;

#define N_NODES 50000
#define DIM     128
#define N_EDGES 800000
#define N_UID   4096
#define LN_EPS  1e-5f
#define RST     132   // padded LDS row stride for fp32 y
#define XST     136   // padded LDS row stride for bf16 x
#define NBUCK   196   // ceil(50000/256) buckets of 256 nodes
#define BCAP    4608  // per-bucket capacity (mean 4096, +8 sigma)
#define PCHUNK  4096
#define NCHUNK  ((N_EDGES + PCHUNK - 1) / PCHUNK)   // 196
#define MAXS    28    // max 32-edge steps per block (L ~ 544 +- 23; 896 = +15 sigma)
#define KST     40    // staging tile k-stride (elements); 80B rows -> spread bank starts

typedef __attribute__((ext_vector_type(8))) short bf16x8;
typedef __attribute__((ext_vector_type(4))) float f32x4;
typedef __attribute__((ext_vector_type(4))) uint  u32x4;

// ---- bf16 pack (storage only; math fp32) ----
__device__ __forceinline__ uint pack_bf16(float a, float b) {   // RNE
    uint ua = __builtin_bit_cast(uint, a);
    uint ub = __builtin_bit_cast(uint, b);
    uint ra = (ua + 0x7fffu + ((ua >> 16) & 1u)) >> 16;
    uint rb = (ub + 0x7fffu + ((ub >> 16) & 1u)) >> 16;
    return ra | (rb << 16);
}

// ---------- prep: emb/W -> bf16, zero bcur, zero pad rows ----------
__global__ __launch_bounds__(256) void prep_kernel(const float* __restrict__ emb, ushort* __restrict__ E,
                                                   const float* __restrict__ W, ushort* __restrict__ WB,
                                                   int* __restrict__ bcur,
                                                   ushort* __restrict__ T1, ushort* __restrict__ T2) {
    int i = blockIdx.x * 256 + threadIdx.x;
    if (i < N_NODES * DIM / 4) {
        const float4 v = ((const float4*)emb)[i];
        uint2 p;
        p.x = pack_bf16(v.x, v.y);
        p.y = pack_bf16(v.z, v.w);
        ((uint2*)E)[i] = p;
    }
    if (i < 3 * DIM * DIM / 4) {
        const float4 v = ((const float4*)W)[i];
        uint2 p;
        p.x = pack_bf16(v.x, v.y);
        p.y = pack_bf16(v.z, v.w);
        ((uint2*)WB)[i] = p;
    }
    if (i < 256) bcur[i] = 0;
    if (i < DIM / 4) {               // zero row N_NODES (pad target: contributes exact 0)
        const uint2 z = make_uint2(0u, 0u);
        ((uint2*)(E  + (size_t)N_NODES * DIM))[i] = z;
        ((uint2*)(T1 + (size_t)N_NODES * DIM))[i] = z;
        ((uint2*)(T2 + (size_t)N_NODES * DIM))[i] = z;
    }
}

// ---------- partition into fixed-capacity padded buckets ----------
__global__ __launch_bounds__(256) void part_kernel(const int* __restrict__ src, const int* __restrict__ dst,
                                                   int* __restrict__ bcur, int* __restrict__ pak) {
    __shared__ int h[256];
    __shared__ int base[256];
    __shared__ int cur[256];
    const int t  = threadIdx.x;
    const int e0 = blockIdx.x * PCHUNK;
    const int e1 = min(e0 + PCHUNK, N_EDGES);
    h[t] = 0;
    __syncthreads();
    for (int i = e0 + t; i < e1; i += 256)
        atomicAdd(&h[dst[i] >> 8], 1);
    __syncthreads();
    if (t < NBUCK && h[t]) base[t] = atomicAdd(&bcur[t], h[t]);
    cur[t] = 0;
    __syncthreads();
    for (int i = e0 + t; i < e1; i += 256) {
        const int s = src[i], d = dst[i];
        const int b = d >> 8;
        const int q = base[b] + atomicAdd(&cur[b], 1);
        if (q < BCAP)
            pak[b * BCAP + q] = (s << 8) | (d & 255);
    }
}

// ---------- per-bucket CSR: count/scan/scatter in LDS; padded layout ----------
__global__ __launch_bounds__(256) void bucket_kernel(const int* __restrict__ pak, const int* __restrict__ bcur,
                                                     int* __restrict__ off, int* __restrict__ degv,
                                                     int* __restrict__ csr) {
    __shared__ int cnt[256];
    __shared__ int pos[256];
    const int b = blockIdx.x, t = threadIdx.x;
    const int e0 = b * BCAP;
    const int m  = min(bcur[b], BCAP);
    cnt[t] = 0;
    __syncthreads();
    for (int i = t; i < m; i += 256) atomicAdd(&cnt[pak[e0 + i] & 255], 1);
    __syncthreads();
    const int v = cnt[t];
    pos[t] = v;
    __syncthreads();
    for (int o = 1; o < 256; o <<= 1) {
        int x = (t >= o) ? pos[t - o] : 0;
        __syncthreads();
        pos[t] += x;
        __syncthreads();
    }
    const int excl = pos[t] - v;
    const int node = b * 256 + t;
    if (node < N_NODES) { off[node] = e0 + excl; degv[node] = v; }
    __syncthreads();
    pos[t] = excl;
    __syncthreads();
    for (int i = t; i < m; i += 256) {
        const int p = pak[e0 + i];
        const int q = atomicAdd(&pos[p & 255], 1);
        csr[e0 + q] = p >> 8;
    }
}

// ---------- fused layer: MFMA selection-matrix aggregation + GEMM + LN + ELU ----------
// Plain-HIP only (no inline asm / global_load_lds / tr-reads).
// 512 thr, 32 nodes/block. Augmented stream [self_i, edges_i] in CSR order,
// padded to 32-edge steps with zero-row N_NODES. Wave w owns dims [16w,16w+16).
// Per step: each lane loads 2 dims x 4 rows (4 uint loads, 3-step reg rotation),
// repacks to k-minor, ds_write_b64 x2 into d-major tile [16][KST]; B-frag is a
// plain contiguous LDS read at [c][8g..8g+8); A-frag from per-(step,node) 32-bit
// run masks + 16-entry LUT; 2 x mfma_16x16x32_bf16 (two 16-node halves).
// Within-wave LDS in-order + program order make single-buffer staging safe.
// C/D: col = lane&15, row = (lane>>4)*4 + reg   [measured m89]
template <bool OUT_BF16>
__global__ __launch_bounds__(512, 4) void layer_kernel(
    const ushort* __restrict__ fin, void* __restrict__ fout,
    const int* __restrict__ off, const int* __restrict__ degv,
    const int* __restrict__ csr, const int* __restrict__ uidmap,
    const ushort* __restrict__ wb, const float* __restrict__ bias,
    const float* __restrict__ gamma, const float* __restrict__ beta, int nrows)
{
    __shared__ ushort xs[32 * XST];        // 8704 B  bf16 x_mean
    __shared__ float  ys[32 * RST];        // 16896 B fp32 y (phases 2/3)
    __shared__ ushort stg[8 * 16 * KST];   // 10240 B staging: per-wave [16 d][KST k]
    __shared__ int    cum[33];
    __shared__ int    cntl[32];
    __shared__ int    narr[32];
    __shared__ int    doffs[32];
    __shared__ int    idsl[MAXS * 32];     // gather ids per stream position
    __shared__ uint   mskl[MAXS * 32];     // per-(step,node) selection mask
    __shared__ uint2  lutl[16];            // 4 bits -> 4 bf16 {0,1}

    const int t = threadIdx.x;
    const int rows = blockIdx.x * 32;

    // ---- prologue: per-node meta + LUT ----
    if (t < 32) {
        const int slot = rows + t;
        int n = 0, dgr = 0, d0o = 0;
        if (slot < nrows) { n = uidmap ? uidmap[slot] : slot; dgr = degv[n]; d0o = off[n]; }
        narr[t] = n; doffs[t] = d0o;
        cntl[t] = (slot < nrows) ? (dgr + 1) : 0;   // self + neighbors
    }
    if (t < 16) {
        const uint e0 = ((t & 1) ? 0x3F80u : 0u) | ((t & 2) ? 0x3F800000u : 0u);
        const uint e1 = ((t & 4) ? 0x3F80u : 0u) | ((t & 8) ? 0x3F800000u : 0u);
        lutl[t] = make_uint2(e0, e1);
    }
    __syncthreads();
    if (t < 32) {
        int sacc = 0;
        for (int i = 0; i <= t; ++i) sacc += cntl[i];
        cum[t + 1] = sacc;
        if (t == 0) cum[0] = 0;
    }
    __syncthreads();
    const int L = cum[32];
    const int S = min((L + 31) >> 5, MAXS);

    // ---- prologue: stream ids + selection masks ----
    for (int p = t; p < S * 32; p += 512) {
        int lo = 0, hi = 32;                       // largest i with cum[i] <= p
        #pragma unroll
        for (int it = 0; it < 5; ++it) {
            const int mid = (lo + hi) >> 1;
            if (cum[mid] <= p) lo = mid; else hi = mid;
        }
        const int i = lo;
        const int j = p - cum[i];
        int id = N_NODES;                          // pad -> zero row
        if (p < L) id = (j == 0) ? narr[i] : csr[doffs[i] + j - 1];
        idsl[p] = id;

        const int i2 = p & 31;                     // mask for (step p>>5, node i2)
        const int base = (p >> 5) << 5;
        const int a = min(max(cum[i2]     - base, 0), 32);
        const int b = min(max(cum[i2 + 1] - base, 0), 32);
        const uint mb = (b >= 32) ? 0xFFFFFFFFu : ((1u << b) - 1u);
        const uint ma = (a >= 32) ? 0xFFFFFFFFu : ((1u << a) - 1u);
        mskl[p] = mb & ~ma;
    }
    __syncthreads();

    // ---- phase 1: MFMA aggregation (no cross-wave coupling) ----
    {
        const int w = t >> 6, l = t & 63;
        const int kq = l & 7;                      // k-quad: k = 4*kq + j
        const int dg = l >> 3;                     // dim pair: d = 2*dg, 2*dg+1
        const int goffb = w * 16 + 2 * dg;         // element offset within row
        ushort* sw = stg + w * (16 * KST);

#define LD4(S_, Q_) { \
            const int bse = (S_) * 32 + 4 * kq; \
            Q_.x = *(const uint*)(fin + (size_t)idsl[bse + 0] * DIM + goffb); \
            Q_.y = *(const uint*)(fin + (size_t)idsl[bse + 1] * DIM + goffb); \
            Q_.z = *(const uint*)(fin + (size_t)idsl[bse + 2] * DIM + goffb); \
            Q_.w = *(const uint*)(fin + (size_t)idsl[bse + 3] * DIM + goffb); }

        uint4 qa, qb, qc;
        LD4(0, qa);
        if (S > 1) { LD4(1, qb); } else qb = qa;
        if (S > 2) { LD4(2, qc); } else qc = qb;

        const int g = l >> 4, c = l & 15;
        const int koct = g * 8;
        const ushort* rp = sw + c * KST + koct;    // B-frag source: [d=c][k=koct..koct+7]
        f32x4 acc0 = f32x4{0, 0, 0, 0}, acc1 = f32x4{0, 0, 0, 0};

        for (int s = 0; s < S; ++s) {
            // repack (4 rows x 2 dims) -> (2 dims x 4 k) and stage d-major
            const uint u0 = (qa.x & 0xffffu) | (qa.y << 16);
            const uint u1 = (qa.z & 0xffffu) | (qa.w << 16);
            const uint u2 = (qa.x >> 16)     | (qa.y & 0xffff0000u);
            const uint u3 = (qa.z >> 16)     | (qa.w & 0xffff0000u);
            *((uint2*)(sw + (2 * dg)     * KST + 4 * kq)) = make_uint2(u0, u1);
            *((uint2*)(sw + (2 * dg + 1) * KST + 4 * kq)) = make_uint2(u2, u3);
            qa = qb; qb = qc;
            if (s + 3 < S) LD4(s + 3, qc);

            // A fragments from run masks (two 16-node halves)
            const uint m0 = mskl[s * 32 + c];
            const uint m1 = mskl[s * 32 + c + 16];
            const uint b0 = (m0 >> koct) & 0xffu;
            const uint b1 = (m1 >> koct) & 0xffu;
            const uint2 p00 = lutl[b0 & 15u], p01 = lutl[b0 >> 4];
            const uint2 p10 = lutl[b1 & 15u], p11 = lutl[b1 >> 4];
            const u32x4 a0w = u32x4{p00.x, p00.y, p01.x, p01.y};
            const u32x4 a1w = u32x4{p10.x, p10.y, p11.x, p11.y};

            // B fragment: contiguous LDS read (same wave wrote it above)
            const u32x4 bwv = *((const u32x4*)rp);
            const bf16x8 bfv = __builtin_bit_cast(bf16x8, bwv);
            acc0 = __builtin_amdgcn_mfma_f32_16x16x32_bf16(__builtin_bit_cast(bf16x8, a0w), bfv, acc0, 0, 0, 0);
            acc1 = __builtin_amdgcn_mfma_f32_16x16x32_bf16(__builtin_bit_cast(bf16x8, a1w), bfv, acc1, 0, 0, 0);
        }
#undef LD4

        // epilogue: normalize by (deg+1), write x_mean bf16 to xs
        const int r0 = g * 4;
        #pragma unroll
        for (int r = 0; r < 4; ++r) {
            const int i0 = r0 + r;
            const float iv0 = 1.0f / (float)max(cum[i0 + 1] - cum[i0], 1);
            xs[i0 * XST + w * 16 + c] = (ushort)pack_bf16(acc0[r] * iv0, 0.0f);
            const int i1 = i0 + 16;
            const float iv1 = 1.0f / (float)max(cum[i1 + 1] - cum[i1], 1);
            xs[i1 * XST + w * 16 + c] = (ushort)pack_bf16(acc1[r] * iv1, 0.0f);
        }
    }
    __syncthreads();

    // ---- phase 2: MFMA y = x @ W^T; 8 waves, rows 2x16, cols 4x32 ----
    {
        const int wave = t >> 6, lane = t & 63;
        const int row_off = (wave >> 2) * 16;
        const int col_off = (wave & 3) * 32;
        const int lm   = lane & 15;
        const int quad = lane >> 4;
        f32x4 acc[2] = {f32x4{0, 0, 0, 0}, f32x4{0, 0, 0, 0}};
        const ushort* xrow = xs + (row_off + lm) * XST + quad * 8;
        const ushort* __restrict__ wrow = wb + (size_t)(col_off + lm) * DIM + quad * 8;
        #pragma unroll
        for (int kk = 0; kk < 4; ++kk) {
            const bf16x8 af = __builtin_bit_cast(bf16x8, *(const u32x4*)(xrow + kk * 32));
            #pragma unroll
            for (int cc = 0; cc < 2; ++cc) {
                const bf16x8 bfr = __builtin_bit_cast(bf16x8,
                    *(const u32x4*)(wrow + (size_t)cc * 16 * DIM + kk * 32));
                acc[cc] = __builtin_amdgcn_mfma_f32_16x16x32_bf16(af, bfr, acc[cc], 0, 0, 0);
            }
        }
        #pragma unroll
        for (int cc = 0; cc < 2; ++cc) {
            #pragma unroll
            for (int r = 0; r < 4; ++r)
                ys[(row_off + quad * 4 + r) * RST + col_off + cc * 16 + lm] = acc[cc][r];
        }
    }
    __syncthreads();

    // ---- phase 3: LN + ELU; 16 threads per row, 8 dims each ----
    {
        const int r   = t >> 4;
        const int seg = t & 15;
        const int db  = seg * 8;
        const float* yr = ys + r * RST + db;
        float vs[8];
        {
            const float4 y0 = ((const float4*)yr)[0];
            const float4 y1 = ((const float4*)yr)[1];
            const float4 b0 = ((const float4*)(bias + db))[0];
            const float4 b1 = ((const float4*)(bias + db))[1];
            vs[0] = y0.x + b0.x; vs[1] = y0.y + b0.y; vs[2] = y0.z + b0.z; vs[3] = y0.w + b0.w;
            vs[4] = y1.x + b1.x; vs[5] = y1.y + b1.y; vs[6] = y1.z + b1.z; vs[7] = y1.w + b1.w;
        }
        float s1 = 0.0f, s2 = 0.0f;
        #pragma unroll
        for (int i = 0; i < 8; ++i) { s1 += vs[i]; s2 += vs[i] * vs[i]; }
        #pragma unroll
        for (int m = 1; m < 16; m <<= 1) {
            s1 += __shfl_xor(s1, m);
            s2 += __shfl_xor(s2, m);
        }
        const float mu  = s1 * (1.0f / 128.0f);
        const float var = s2 * (1.0f / 128.0f) - mu * mu;
        const float rs  = rsqrtf(var + LN_EPS);
        float ov[8];
        {
            const float4 g0 = ((const float4*)(gamma + db))[0];
            const float4 g1 = ((const float4*)(gamma + db))[1];
            const float4 t0 = ((const float4*)(beta + db))[0];
            const float4 t1 = ((const float4*)(beta + db))[1];
            float z;
            z = (vs[0] - mu) * rs * g0.x + t0.x; ov[0] = (z > 0.0f) ? z : __expf(z) - 1.0f;
            z = (vs[1] - mu) * rs * g0.y + t0.y; ov[1] = (z > 0.0f) ? z : __expf(z) - 1.0f;
            z = (vs[2] - mu) * rs * g0.z + t0.z; ov[2] = (z > 0.0f) ? z : __expf(z) - 1.0f;
            z = (vs[3] - mu) * rs * g0.w + t0.w; ov[3] = (z > 0.0f) ? z : __expf(z) - 1.0f;
            z = (vs[4] - mu) * rs * g1.x + t1.x; ov[4] = (z > 0.0f) ? z : __expf(z) - 1.0f;
            z = (vs[5] - mu) * rs * g1.y + t1.y; ov[5] = (z > 0.0f) ? z : __expf(z) - 1.0f;
            z = (vs[6] - mu) * rs * g1.z + t1.z; ov[6] = (z > 0.0f) ? z : __expf(z) - 1.0f;
            z = (vs[7] - mu) * rs * g1.w + t1.w; ov[7] = (z > 0.0f) ? z : __expf(z) - 1.0f;
        }
        const int slot = rows + r;
        if (slot < nrows) {
            if (OUT_BF16) {
                uint4 p;
                p.x = pack_bf16(ov[0], ov[1]);
                p.y = pack_bf16(ov[2], ov[3]);
                p.z = pack_bf16(ov[4], ov[5]);
                p.w = pack_bf16(ov[6], ov[7]);
                *((uint4*)((ushort*)fout + (size_t)slot * DIM + db)) = p;
            } else {
                float* op = (float*)fout + (size_t)slot * DIM + db;
                ((float4*)op)[0] = make_float4(ov[0], ov[1], ov[2], ov[3]);
                ((float4*)op)[1] = make_float4(ov[4], ov[5], ov[6], ov[7]);
            }
        }
    }
}

extern "C" void kernel_launch(void* const* d_in, const int* in_sizes, int n_in,
                              void* d_out, int out_size, void* d_ws, size_t ws_size,
                              hipStream_t stream) {
    const float* emb   = (const float*)d_in[0];
    const float* W     = (const float*)d_in[1];
    const float* bias  = (const float*)d_in[2];
    const float* gamma = (const float*)d_in[3];
    const float* beta  = (const float*)d_in[4];
    const int*   src   = (const int*)d_in[5];
    const int*   dst   = (const int*)d_in[6];
    const int*   uid   = (const int*)d_in[7];

    // workspace (~46 MB); feature buffers have a zero pad row at index N_NODES
    const size_t FROW = (size_t)(N_NODES + 1) * DIM;
    ushort* E    = (ushort*)d_ws;
    ushort* T1   = E + FROW;
    ushort* T2   = T1 + FROW;
    ushort* WB   = T2 + FROW;                         // 3*128*128 bf16
    int*    off  = (int*)(WB + 3 * DIM * DIM);        // 50000 (+pad)
    int*    degv = off + (N_NODES + 4);               // 50000 (+pad)
    int*    bcur = degv + (N_NODES + 4);              // 256
    int*    pak  = bcur + 256;                        // NBUCK*BCAP packed
    int*    csr  = pak + NBUCK * BCAP;                // NBUCK*BCAP (+in-bucket slack)

    prep_kernel<<<(N_NODES * DIM / 4 + 255) / 256, 256, 0, stream>>>(emb, E, W, WB, bcur, T1, T2);
    part_kernel<<<NCHUNK, 256, 0, stream>>>(src, dst, bcur, pak);
    bucket_kernel<<<NBUCK, 256, 0, stream>>>(pak, bcur, off, degv, csr);

    const int lblk = (N_NODES + 31) / 32;             // 1563

    layer_kernel<true><<<lblk, 512, 0, stream>>>(E, T1, off, degv, csr, nullptr, WB,
                                                 bias, gamma, beta, N_NODES);
    layer_kernel<true><<<lblk, 512, 0, stream>>>(T1, T2, off, degv, csr, nullptr, WB + DIM * DIM,
                                                 bias + DIM, gamma + DIM, beta + DIM, N_NODES);
    layer_kernel<false><<<N_UID / 32, 512, 0, stream>>>(T2, (float*)d_out, off, degv, csr, uid,
                                                        WB + 2 * DIM * DIM, bias + 2 * DIM,
                                                        gamma + 2 * DIM, beta + 2 * DIM, N_UID);
}

// Round 9
// 261.179 us; speedup vs baseline: 1.1045x; 1.1045x over previous
//
#include <hip/hip_runtime.h>
#include <math.h>

typedef unsigned int   uint;
typedef unsigned short ushort;
typedef unsigned char  uchar;

#define N_NODES 50000
#define DIM     128
#define N_EDGES 800000
#define N_UID   4096
#define LN_EPS  1e-5f
#define RST     132   // padded LDS row stride for fp32 y (132*4 B)
#define XST     136   // padded LDS row stride for bf16 x
#define NBUCK   196   // ceil(50000/256) buckets of 256 nodes
#define BCAP    4608  // per-bucket capacity (mean 4096, +8 sigma)
#define PCHUNK  4096  // edges per partition chunk
#define NCHUNK  ((N_EDGES + PCHUNK - 1) / PCHUNK)   // 196
#define QBLK    (N_NODES / 16)   // 3125 (exact)
#define WBLK    48               // 3*128*128/4 float4s / 256
#define MROW    50004            // meta rows (padded)
#define NR      16               // nodes per layer block (256 thr) -> 12.8KB LDS, 8 blocks/CU

typedef __attribute__((ext_vector_type(8))) short bf16x8;
typedef __attribute__((ext_vector_type(4))) float f32x4;
typedef __attribute__((ext_vector_type(4))) uint  u32x4;

// ---- bf16 pack (storage only; math fp32) ----
__device__ __forceinline__ uint pack_bf16(float a, float b) {   // RNE
    uint ua = __builtin_bit_cast(uint, a);
    uint ub = __builtin_bit_cast(uint, b);
    uint ra = (ua + 0x7fffu + ((ua >> 16) & 1u)) >> 16;
    uint rb = (ub + 0x7fffu + ((ub >> 16) & 1u)) >> 16;
    return ra | (rb << 16);
}

// ---------- prep: emb -> int8 affine rows (16 lanes/row), W -> bf16, zero bcur/meta pads ----------
__global__ __launch_bounds__(256) void prep_kernel(const float* __restrict__ emb,
                                                   uchar* __restrict__ Q0, float2* __restrict__ M0,
                                                   const float* __restrict__ W, ushort* __restrict__ WB,
                                                   int* __restrict__ bcur,
                                                   float2* __restrict__ M1, float2* __restrict__ M2) {
    const int t = threadIdx.x, b = blockIdx.x;
    if (b < QBLK) {
        const int row = b * 16 + (t >> 4);
        const int seg = t & 15;
        const float* rp = emb + (size_t)row * DIM + seg * 8;
        const float4 v0 = ((const float4*)rp)[0];
        const float4 v1 = ((const float4*)rp)[1];
        float vs[8] = {v0.x, v0.y, v0.z, v0.w, v1.x, v1.y, v1.z, v1.w};
        float mn = vs[0], mx = vs[0];
        #pragma unroll
        for (int j = 1; j < 8; ++j) { mn = fminf(mn, vs[j]); mx = fmaxf(mx, vs[j]); }
        #pragma unroll
        for (int m = 1; m < 16; m <<= 1) {
            mn = fminf(mn, __shfl_xor(mn, m));
            mx = fmaxf(mx, __shfl_xor(mx, m));
        }
        const float rng = mx - mn;
        const float rcp = (rng > 0.0f) ? 255.0f / rng : 0.0f;
        uint bq[8];
        #pragma unroll
        for (int j = 0; j < 8; ++j)
            bq[j] = (uint)fminf(255.0f, fmaf(vs[j] - mn, rcp, 0.5f));
        uint2 q;
        q.x = bq[0] | (bq[1] << 8) | (bq[2] << 16) | (bq[3] << 24);
        q.y = bq[4] | (bq[5] << 8) | (bq[6] << 16) | (bq[7] << 24);
        ((uint2*)(Q0 + (size_t)row * DIM))[seg] = q;
        if (seg == 0) M0[row] = make_float2(rng * (1.0f / 255.0f), mn);
    } else if (b < QBLK + WBLK) {
        const int i = (b - QBLK) * 256 + t;      // < 12288 exactly
        const float4 v = ((const float4*)W)[i];
        uint2 p;
        p.x = pack_bf16(v.x, v.y);
        p.y = pack_bf16(v.z, v.w);
        ((uint2*)WB)[i] = p;
    } else {
        if (t < 256) bcur[t] = 0;
        if (t == 0) {                            // zero-meta pad row: contributes exactly 0
            M0[N_NODES] = make_float2(0.0f, 0.0f);
            M1[N_NODES] = make_float2(0.0f, 0.0f);
            M2[N_NODES] = make_float2(0.0f, 0.0f);
        }
    }
}

// ---------- partition into fixed-capacity padded buckets ----------
__global__ __launch_bounds__(256) void part_kernel(const int* __restrict__ src, const int* __restrict__ dst,
                                                   int* __restrict__ bcur, int* __restrict__ pak) {
    __shared__ int h[256];
    __shared__ int base[256];
    __shared__ int cur[256];
    const int t  = threadIdx.x;
    const int e0 = blockIdx.x * PCHUNK;
    const int e1 = min(e0 + PCHUNK, N_EDGES);
    h[t] = 0;
    __syncthreads();
    for (int i = e0 + t; i < e1; i += 256)
        atomicAdd(&h[dst[i] >> 8], 1);
    __syncthreads();
    if (t < NBUCK && h[t]) base[t] = atomicAdd(&bcur[t], h[t]);
    cur[t] = 0;
    __syncthreads();
    for (int i = e0 + t; i < e1; i += 256) {
        const int s = src[i], d = dst[i];
        const int b = d >> 8;
        const int q = base[b] + atomicAdd(&cur[b], 1);
        if (q < BCAP)                               // safety guard (never fires)
            pak[b * BCAP + q] = (s << 8) | (d & 255);
    }
}

// ---------- per-bucket CSR: count/scan/scatter in LDS; padded layout ----------
__global__ __launch_bounds__(256) void bucket_kernel(const int* __restrict__ pak, const int* __restrict__ bcur,
                                                     int* __restrict__ off, int* __restrict__ degv,
                                                     int* __restrict__ csr) {
    __shared__ int cnt[256];
    __shared__ int pos[256];
    const int b = blockIdx.x, t = threadIdx.x;
    const int e0 = b * BCAP;
    const int m  = min(bcur[b], BCAP);
    cnt[t] = 0;
    __syncthreads();
    for (int i = t; i < m; i += 256) atomicAdd(&cnt[pak[e0 + i] & 255], 1);
    __syncthreads();
    const int v = cnt[t];
    pos[t] = v;
    __syncthreads();
    for (int o = 1; o < 256; o <<= 1) {
        int x = (t >= o) ? pos[t - o] : 0;
        __syncthreads();
        pos[t] += x;
        __syncthreads();
    }
    const int excl = pos[t] - v;
    const int node = b * 256 + t;
    if (node < N_NODES) { off[node] = e0 + excl; degv[node] = v; }
    __syncthreads();
    pos[t] = excl;
    __syncthreads();
    for (int i = t; i < m; i += 256) {
        const int p = pak[e0 + i];
        const int q = atomicAdd(&pos[p & 255], 1);
        csr[e0 + q] = p >> 8;
    }
}

// ---------- fused layer: int8-affine gather + MFMA GEMM + LN + ELU (+requant out) ----------
// RE-TILED round-5 kernel: 256 threads, 16 nodes/block (12.8KB LDS -> up to 8
// blocks/CU = 32 waves, vs 512-thr version's ~14). Single-variable experiment:
// residency/occupancy is the only knob changed vs the proven 47us kernel.
// Agg: 16-lane stream per node, 8 rows in flight, zero-meta pad row.
// C/D: col = lane&15, row = (lane>>4)*4 + reg   [measured m89]
template <bool OUT_FP32>
__global__ __launch_bounds__(256, 8) void layer_kernel(
    const uchar* __restrict__ qin, const float2* __restrict__ meta_in,
    uchar* __restrict__ qout, float2* __restrict__ meta_out, float* __restrict__ fpout,
    const int* __restrict__ off, const int* __restrict__ degv,
    const int* __restrict__ csr, const int* __restrict__ uidmap,
    const ushort* __restrict__ wb, const float* __restrict__ bias,
    const float* __restrict__ gamma, const float* __restrict__ beta, int nrows)
{
    __shared__ ushort xs[NR * XST];   // 4352 B  (bf16 x_mean)
    __shared__ float  ys[NR * RST];   // 8448 B  (fp32 y)
    const int t = threadIdx.x;
    const int rows = blockIdx.x * NR;

    // ---- phase 1: aggregate (int8 gather, 8 rows in flight) ----
    {
        const int lx   = t & 15;                 // covers elems lx*8 .. lx*8+7
        const int st   = t >> 4;                 // node slot 0..15
        const int slot = rows + st;
        const bool valid = slot < nrows;
        int n = 0;
        if (valid) n = uidmap ? uidmap[slot] : slot;
        const int d0 = off[n];
        const int deg = valid ? degv[n] : 0;
        const int total = deg + 1;               // self + neighbors

        float a[8] = {0,0,0,0,0,0,0,0};
        float O = 0.0f;
        const int rounds = (total + 7) >> 3;
        int id[8], idn[8];
        uint2 qv[8];
        float2 mt[8];

#define LIDS(ID, BASE) { _Pragma("unroll") for (int k = 0; k < 8; ++k) {        \
            const int pos = (BASE) + k;                                         \
            const int c = csr[d0 + ((pos > 0) ? pos - 1 : 0)];                  \
            ID[k] = (pos == 0) ? n : ((pos < total) ? c : N_NODES); } }

        LIDS(id, 0);
        for (int r = 0; r < rounds; ++r) {
            #pragma unroll
            for (int k = 0; k < 8; ++k) {
                qv[k] = ((const uint2*)(qin + (size_t)id[k] * DIM))[lx];
                mt[k] = meta_in[id[k]];
            }
            const bool more = (r + 1 < rounds);
            if (more) LIDS(idn, (r + 1) * 8);
            #pragma unroll
            for (int k = 0; k < 8; ++k) {
                const float s = mt[k].x;
                const uint x0 = qv[k].x, x1 = qv[k].y;
                a[0] = fmaf((float)(x0 & 0xffu),         s, a[0]);
                a[1] = fmaf((float)((x0 >> 8) & 0xffu),  s, a[1]);
                a[2] = fmaf((float)((x0 >> 16) & 0xffu), s, a[2]);
                a[3] = fmaf((float)(x0 >> 24),           s, a[3]);
                a[4] = fmaf((float)(x1 & 0xffu),         s, a[4]);
                a[5] = fmaf((float)((x1 >> 8) & 0xffu),  s, a[5]);
                a[6] = fmaf((float)((x1 >> 16) & 0xffu), s, a[6]);
                a[7] = fmaf((float)(x1 >> 24),           s, a[7]);
                O += mt[k].y;
            }
            if (more) {
                #pragma unroll
                for (int k = 0; k < 8; ++k) id[k] = idn[k];
            }
        }
#undef LIDS

        const float iv = 1.0f / (float)total;
        uint4 p;
        p.x = pack_bf16((a[0] + O) * iv, (a[1] + O) * iv);
        p.y = pack_bf16((a[2] + O) * iv, (a[3] + O) * iv);
        p.z = pack_bf16((a[4] + O) * iv, (a[5] + O) * iv);
        p.w = pack_bf16((a[6] + O) * iv, (a[7] + O) * iv);
        *((uint4*)(xs + st * XST + lx * 8)) = p;
    }
    __syncthreads();

    // ---- phase 2: MFMA y = x @ W^T; 4 waves, rows 16, cols 4x32 ----
    {
        const int wave = t >> 6, lane = t & 63;
        const int col_off = wave * 32;
        const int lm   = lane & 15;
        const int quad = lane >> 4;
        f32x4 acc[2] = {f32x4{0,0,0,0}, f32x4{0,0,0,0}};
        const ushort* xrow = xs + lm * XST + quad * 8;               // LDS
        const ushort* __restrict__ wrow = wb + (size_t)(col_off + lm) * DIM + quad * 8;
        #pragma unroll
        for (int kk = 0; kk < 4; ++kk) {
            const bf16x8 af = __builtin_bit_cast(bf16x8, *(const u32x4*)(xrow + kk * 32));
            #pragma unroll
            for (int c = 0; c < 2; ++c) {
                const bf16x8 bfr = __builtin_bit_cast(bf16x8,
                    *(const u32x4*)(wrow + (size_t)c * 16 * DIM + kk * 32));
                acc[c] = __builtin_amdgcn_mfma_f32_16x16x32_bf16(af, bfr, acc[c], 0, 0, 0);
            }
        }
        #pragma unroll
        for (int c = 0; c < 2; ++c) {
            #pragma unroll
            for (int r = 0; r < 4; ++r)
                ys[(quad * 4 + r) * RST + col_off + c * 16 + lm] = acc[c][r];
        }
    }
    __syncthreads();

    // ---- phase 3: LN + ELU; 16 threads per row; requant (or fp32 out) ----
    {
        const int r   = t >> 4;              // row 0..15
        const int seg = t & 15;              // 0..15
        const int db  = seg * 8;
        const float* yr = ys + r * RST + db;
        float vs[8];
        {
            const float4 y0 = ((const float4*)yr)[0];
            const float4 y1 = ((const float4*)yr)[1];
            const float4 b0 = ((const float4*)(bias + db))[0];
            const float4 b1 = ((const float4*)(bias + db))[1];
            vs[0] = y0.x + b0.x; vs[1] = y0.y + b0.y; vs[2] = y0.z + b0.z; vs[3] = y0.w + b0.w;
            vs[4] = y1.x + b1.x; vs[5] = y1.y + b1.y; vs[6] = y1.z + b1.z; vs[7] = y1.w + b1.w;
        }
        float s1 = 0.0f, s2 = 0.0f;
        #pragma unroll
        for (int i = 0; i < 8; ++i) { s1 += vs[i]; s2 += vs[i] * vs[i]; }
        #pragma unroll
        for (int m = 1; m < 16; m <<= 1) {
            s1 += __shfl_xor(s1, m);
            s2 += __shfl_xor(s2, m);
        }
        const float mu  = s1 * (1.0f / 128.0f);
        const float var = s2 * (1.0f / 128.0f) - mu * mu;
        const float rs  = rsqrtf(var + LN_EPS);
        float ov[8];
        {
            const float4 g0 = ((const float4*)(gamma + db))[0];
            const float4 g1 = ((const float4*)(gamma + db))[1];
            const float4 t0 = ((const float4*)(beta + db))[0];
            const float4 t1 = ((const float4*)(beta + db))[1];
            float z;
            z = (vs[0] - mu) * rs * g0.x + t0.x; ov[0] = (z > 0.0f) ? z : __expf(z) - 1.0f;
            z = (vs[1] - mu) * rs * g0.y + t0.y; ov[1] = (z > 0.0f) ? z : __expf(z) - 1.0f;
            z = (vs[2] - mu) * rs * g0.z + t0.z; ov[2] = (z > 0.0f) ? z : __expf(z) - 1.0f;
            z = (vs[3] - mu) * rs * g0.w + t0.w; ov[3] = (z > 0.0f) ? z : __expf(z) - 1.0f;
            z = (vs[4] - mu) * rs * g1.x + t1.x; ov[4] = (z > 0.0f) ? z : __expf(z) - 1.0f;
            z = (vs[5] - mu) * rs * g1.y + t1.y; ov[5] = (z > 0.0f) ? z : __expf(z) - 1.0f;
            z = (vs[6] - mu) * rs * g1.z + t1.z; ov[6] = (z > 0.0f) ? z : __expf(z) - 1.0f;
            z = (vs[7] - mu) * rs * g1.w + t1.w; ov[7] = (z > 0.0f) ? z : __expf(z) - 1.0f;
        }
        const int slot = rows + r;
        if (OUT_FP32) {
            if (slot < nrows) {
                float* op = fpout + (size_t)slot * DIM + db;
                ((float4*)op)[0] = make_float4(ov[0], ov[1], ov[2], ov[3]);
                ((float4*)op)[1] = make_float4(ov[4], ov[5], ov[6], ov[7]);
            }
        } else {
            float mn = ov[0], mx = ov[0];
            #pragma unroll
            for (int j = 1; j < 8; ++j) { mn = fminf(mn, ov[j]); mx = fmaxf(mx, ov[j]); }
            #pragma unroll
            for (int m = 1; m < 16; m <<= 1) {
                mn = fminf(mn, __shfl_xor(mn, m));
                mx = fmaxf(mx, __shfl_xor(mx, m));
            }
            if (slot < nrows) {
                const float rng = mx - mn;
                const float rcp = (rng > 0.0f) ? 255.0f / rng : 0.0f;
                uint bq[8];
                #pragma unroll
                for (int j = 0; j < 8; ++j)
                    bq[j] = (uint)fminf(255.0f, fmaf(ov[j] - mn, rcp, 0.5f));
                uint2 q;
                q.x = bq[0] | (bq[1] << 8) | (bq[2] << 16) | (bq[3] << 24);
                q.y = bq[4] | (bq[5] << 8) | (bq[6] << 16) | (bq[7] << 24);
                ((uint2*)(qout + (size_t)slot * DIM))[seg] = q;
                if (seg == 0) meta_out[slot] = make_float2(rng * (1.0f / 255.0f), mn);
            }
        }
    }
}

extern "C" void kernel_launch(void* const* d_in, const int* in_sizes, int n_in,
                              void* d_out, int out_size, void* d_ws, size_t ws_size,
                              hipStream_t stream) {
    const float* emb   = (const float*)d_in[0];
    const float* W     = (const float*)d_in[1];
    const float* bias  = (const float*)d_in[2];
    const float* gamma = (const float*)d_in[3];
    const float* beta  = (const float*)d_in[4];
    const int*   src   = (const int*)d_in[5];
    const int*   dst   = (const int*)d_in[6];
    const int*   uid   = (const int*)d_in[7];

    // workspace layout (~29 MB); Q buffers have an (unread-payload) pad row at index
    // N_NODES whose META is zero -> dequantizes to exact 0 (tail-clamp target)
    const size_t QSZ = (size_t)(N_NODES + 1) * DIM;   // bytes per int8 feature buffer
    uchar*  Q0  = (uchar*)d_ws;
    uchar*  Q1  = Q0 + QSZ;
    uchar*  Q2  = Q1 + QSZ;
    ushort* WB  = (ushort*)(Q2 + QSZ);                // 3*128*128 bf16
    float2* M0  = (float2*)(WB + 3 * DIM * DIM);      // MROW float2
    float2* M1  = M0 + MROW;
    float2* M2  = M1 + MROW;
    int*    off  = (int*)(M2 + MROW);                 // 50000 (+pad)
    int*    degv = off + (N_NODES + 4);               // 50000 (+pad)
    int*    bcur = degv + (N_NODES + 4);              // 256
    int*    pak  = bcur + 256;                        // NBUCK*BCAP packed (src<<8)|(dst&255)
    int*    csr  = pak + NBUCK * BCAP;                // NBUCK*BCAP (+in-bucket slack)

    prep_kernel<<<QBLK + WBLK + 1, 256, 0, stream>>>(emb, Q0, M0, W, WB, bcur, M1, M2);
    part_kernel<<<NCHUNK, 256, 0, stream>>>(src, dst, bcur, pak);
    bucket_kernel<<<NBUCK, 256, 0, stream>>>(pak, bcur, off, degv, csr);

    const int lblk = (N_NODES + NR - 1) / NR;         // 3125

    // layer 1: Q0 -> Q1
    layer_kernel<false><<<lblk, 256, 0, stream>>>(Q0, M0, Q1, M1, nullptr,
                                                  off, degv, csr, nullptr, WB,
                                                  bias, gamma, beta, N_NODES);
    // layer 2: Q1 -> Q2
    layer_kernel<false><<<lblk, 256, 0, stream>>>(Q1, M1, Q2, M2, nullptr,
                                                  off, degv, csr, nullptr, WB + DIM * DIM,
                                                  bias + DIM, gamma + DIM, beta + DIM, N_NODES);
    // layer 3: uid nodes only, Q2 -> d_out (fp32, no requant)
    layer_kernel<true><<<N_UID / NR, 256, 0, stream>>>(Q2, M2, nullptr, nullptr, (float*)d_out,
                                                       off, degv, csr, uid, WB + 2 * DIM * DIM,
                                                       bias + 2 * DIM, gamma + 2 * DIM,
                                                       beta + 2 * DIM, N_UID);
}

// Round 10
// 203.684 us; speedup vs baseline: 1.4163x; 1.2823x over previous
//
#include <hip/hip_runtime.h>
#include <math.h>

typedef unsigned int   uint;
typedef unsigned short ushort;
typedef unsigned char  uchar;

#define N_NODES 50000
#define DIM     128
#define N_EDGES 800000
#define N_UID   4096
#define LN_EPS  1e-5f
#define RST     132   // padded LDS row stride for fp32 y (132*4 B)
#define XST     136   // padded LDS row stride for bf16 x
#define BSH     6     // bucket shift: 64-node buckets
#define BND     64    // nodes per bucket
#define NBUCK   782   // ceil(50000/64)
#define BCAP    1280  // per-bucket capacity (mean 1024, sigma~32 -> +8 sigma)
#define PCHUNK  2048  // edges per partition chunk
#define NCHUNK  ((N_EDGES + PCHUNK - 1) / PCHUNK)   // 391
#define QBLK    (N_NODES / 16)   // 3125 (exact)
#define WBLK    48               // 3*128*128/4 float4s / 256
#define MROW    50004            // meta rows (padded)

typedef __attribute__((ext_vector_type(8))) short bf16x8;
typedef __attribute__((ext_vector_type(4))) float f32x4;
typedef __attribute__((ext_vector_type(4))) uint  u32x4;

// ---- bf16 pack (storage only; math fp32) ----
__device__ __forceinline__ uint pack_bf16(float a, float b) {   // RNE
    uint ua = __builtin_bit_cast(uint, a);
    uint ub = __builtin_bit_cast(uint, b);
    uint ra = (ua + 0x7fffu + ((ua >> 16) & 1u)) >> 16;
    uint rb = (ub + 0x7fffu + ((ub >> 16) & 1u)) >> 16;
    return ra | (rb << 16);
}

// ---------- prep: emb -> int8 affine rows (16 lanes/row), W -> bf16, zero bcur/meta pads ----------
__global__ __launch_bounds__(256) void prep_kernel(const float* __restrict__ emb,
                                                   uchar* __restrict__ Q0, float2* __restrict__ M0,
                                                   const float* __restrict__ W, ushort* __restrict__ WB,
                                                   int* __restrict__ bcur,
                                                   float2* __restrict__ M1, float2* __restrict__ M2) {
    const int t = threadIdx.x, b = blockIdx.x;
    if (b < QBLK) {
        const int row = b * 16 + (t >> 4);
        const int seg = t & 15;
        const float* rp = emb + (size_t)row * DIM + seg * 8;
        const float4 v0 = ((const float4*)rp)[0];
        const float4 v1 = ((const float4*)rp)[1];
        float vs[8] = {v0.x, v0.y, v0.z, v0.w, v1.x, v1.y, v1.z, v1.w};
        float mn = vs[0], mx = vs[0];
        #pragma unroll
        for (int j = 1; j < 8; ++j) { mn = fminf(mn, vs[j]); mx = fmaxf(mx, vs[j]); }
        #pragma unroll
        for (int m = 1; m < 16; m <<= 1) {
            mn = fminf(mn, __shfl_xor(mn, m));
            mx = fmaxf(mx, __shfl_xor(mx, m));
        }
        const float rng = mx - mn;
        const float rcp = (rng > 0.0f) ? 255.0f / rng : 0.0f;
        uint bq[8];
        #pragma unroll
        for (int j = 0; j < 8; ++j)
            bq[j] = (uint)fminf(255.0f, fmaf(vs[j] - mn, rcp, 0.5f));
        uint2 q;
        q.x = bq[0] | (bq[1] << 8) | (bq[2] << 16) | (bq[3] << 24);
        q.y = bq[4] | (bq[5] << 8) | (bq[6] << 16) | (bq[7] << 24);
        ((uint2*)(Q0 + (size_t)row * DIM))[seg] = q;
        if (seg == 0) M0[row] = make_float2(rng * (1.0f / 255.0f), mn);
    } else if (b < QBLK + WBLK) {
        const int i = (b - QBLK) * 256 + t;      // < 12288 exactly
        const float4 v = ((const float4*)W)[i];
        uint2 p;
        p.x = pack_bf16(v.x, v.y);
        p.y = pack_bf16(v.z, v.w);
        ((uint2*)WB)[i] = p;
    } else {
        for (int i = t; i < NBUCK; i += 256) bcur[i] = 0;
        if (t == 0) {                            // zero-meta pad row: contributes exactly 0
            M0[N_NODES] = make_float2(0.0f, 0.0f);
            M1[N_NODES] = make_float2(0.0f, 0.0f);
            M2[N_NODES] = make_float2(0.0f, 0.0f);
        }
    }
}

// ---------- partition into fixed-capacity padded 64-node buckets ----------
// 391 blocks of 2048 edges (2x grid, half work vs 4096): part was grid-starved.
__global__ __launch_bounds__(256) void part_kernel(const int* __restrict__ src, const int* __restrict__ dst,
                                                   int* __restrict__ bcur, int* __restrict__ pak) {
    __shared__ int h[NBUCK];
    __shared__ int base[NBUCK];
    __shared__ int cur[NBUCK];
    const int t  = threadIdx.x;
    const int e0 = blockIdx.x * PCHUNK;
    const int e1 = min(e0 + PCHUNK, N_EDGES);
    for (int i = t; i < NBUCK; i += 256) h[i] = 0;
    __syncthreads();
    for (int i = e0 + t; i < e1; i += 256)
        atomicAdd(&h[dst[i] >> BSH], 1);
    __syncthreads();
    for (int i = t; i < NBUCK; i += 256) {
        if (h[i]) base[i] = atomicAdd(&bcur[i], h[i]);
        cur[i] = 0;
    }
    __syncthreads();
    for (int i = e0 + t; i < e1; i += 256) {
        const int s = src[i], d = dst[i];
        const int b = d >> BSH;
        const int q = base[b] + atomicAdd(&cur[b], 1);
        if (q < BCAP)                               // +8 sigma guard (never fires)
            pak[b * BCAP + q] = (s << BSH) | (d & (BND - 1));
    }
}

// ---------- per-bucket CSR: count/scan/scatter in LDS; padded layout ----------
// 782 blocks (~3/CU, was 196/0.8): each handles ~1024 edges / 64 nodes.
__global__ __launch_bounds__(256) void bucket_kernel(const int* __restrict__ pak, const int* __restrict__ bcur,
                                                     int* __restrict__ off, int* __restrict__ degv,
                                                     int* __restrict__ csr) {
    __shared__ int cnt[BND];
    __shared__ int pos[BND];
    const int b = blockIdx.x, t = threadIdx.x;
    const int e0 = b * BCAP;
    const int m  = min(bcur[b], BCAP);
    if (t < BND) cnt[t] = 0;
    __syncthreads();
    for (int i = t; i < m; i += 256) atomicAdd(&cnt[pak[e0 + i] & (BND - 1)], 1);
    __syncthreads();
    const int v = (t < BND) ? cnt[t] : 0;
    if (t < BND) pos[t] = v;
    __syncthreads();
    for (int o = 1; o < BND; o <<= 1) {
        int x = 0;
        if (t < BND && t >= o) x = pos[t - o];
        __syncthreads();
        if (t < BND) pos[t] += x;
        __syncthreads();
    }
    const int excl = (t < BND) ? (pos[t] - v) : 0;
    const int node = b * BND + t;
    if (t < BND && node < N_NODES) { off[node] = e0 + excl; degv[node] = v; }
    __syncthreads();
    if (t < BND) pos[t] = excl;                  // reuse as cursor
    __syncthreads();
    for (int i = t; i < m; i += 256) {
        const int p = pak[e0 + i];
        const int q = atomicAdd(&pos[p & (BND - 1)], 1);
        csr[e0 + q] = p >> BSH;
    }
}

// ---------- fused layer: int8-affine gather + MFMA GEMM + LN + ELU (+requant out) ----------
// Template on thread count: NT=512 (r5-proven config, 32 nodes/block) vs NT=256
// (16 nodes/block, 12.8KB LDS -> 8 blocks/CU static). (NT,4) bounds: VGPR cap 128
// -> NO spill (r9 lesson: (256,8) forced 32 VGPR -> 100MB scratch traffic).
// Agg: 16-lane stream per node, 8 rows in flight, zero-meta pad row.
// C/D: col = lane&15, row = (lane>>4)*4 + reg   [measured m89]
template <int NT, bool OUT_FP32>
__global__ __launch_bounds__(NT, 4) void layer_kernel(
    const uchar* __restrict__ qin, const float2* __restrict__ meta_in,
    uchar* __restrict__ qout, float2* __restrict__ meta_out, float* __restrict__ fpout,
    const int* __restrict__ off, const int* __restrict__ degv,
    const int* __restrict__ csr, const int* __restrict__ uidmap,
    const ushort* __restrict__ wb, const float* __restrict__ bias,
    const float* __restrict__ gamma, const float* __restrict__ beta, int nrows)
{
    constexpr int NRT = NT / 16;           // nodes per block
    __shared__ ushort xs[NRT * XST];       // bf16 x_mean
    __shared__ float  ys[NRT * RST];       // fp32 y
    const int t = threadIdx.x;
    const int rows = blockIdx.x * NRT;

    // ---- phase 1: aggregate (int8 gather, 8 rows in flight) ----
    {
        const int lx   = t & 15;                 // covers elems lx*8 .. lx*8+7
        const int st   = t >> 4;                 // node slot 0..NRT-1
        const int slot = rows + st;
        const bool valid = slot < nrows;
        int n = 0;
        if (valid) n = uidmap ? uidmap[slot] : slot;
        const int d0 = off[n];
        const int deg = valid ? degv[n] : 0;
        const int total = deg + 1;               // self + neighbors

        float a[8] = {0,0,0,0,0,0,0,0};
        float O = 0.0f;
        const int rounds = (total + 7) >> 3;
        int id[8], idn[8];
        uint2 qv[8];
        float2 mt[8];

#define LIDS(ID, BASE) { _Pragma("unroll") for (int k = 0; k < 8; ++k) {        \
            const int pos = (BASE) + k;                                         \
            const int c = csr[d0 + ((pos > 0) ? pos - 1 : 0)];                  \
            ID[k] = (pos == 0) ? n : ((pos < total) ? c : N_NODES); } }

        LIDS(id, 0);
        for (int r = 0; r < rounds; ++r) {
            #pragma unroll
            for (int k = 0; k < 8; ++k) {
                qv[k] = ((const uint2*)(qin + (size_t)id[k] * DIM))[lx];
                mt[k] = meta_in[id[k]];
            }
            const bool more = (r + 1 < rounds);
            if (more) LIDS(idn, (r + 1) * 8);
            #pragma unroll
            for (int k = 0; k < 8; ++k) {
                const float s = mt[k].x;
                const uint x0 = qv[k].x, x1 = qv[k].y;
                a[0] = fmaf((float)(x0 & 0xffu),         s, a[0]);
                a[1] = fmaf((float)((x0 >> 8) & 0xffu),  s, a[1]);
                a[2] = fmaf((float)((x0 >> 16) & 0xffu), s, a[2]);
                a[3] = fmaf((float)(x0 >> 24),           s, a[3]);
                a[4] = fmaf((float)(x1 & 0xffu),         s, a[4]);
                a[5] = fmaf((float)((x1 >> 8) & 0xffu),  s, a[5]);
                a[6] = fmaf((float)((x1 >> 16) & 0xffu), s, a[6]);
                a[7] = fmaf((float)(x1 >> 24),           s, a[7]);
                O += mt[k].y;
            }
            if (more) {
                #pragma unroll
                for (int k = 0; k < 8; ++k) id[k] = idn[k];
            }
        }
#undef LIDS

        const float iv = 1.0f / (float)total;
        uint4 p;
        p.x = pack_bf16((a[0] + O) * iv, (a[1] + O) * iv);
        p.y = pack_bf16((a[2] + O) * iv, (a[3] + O) * iv);
        p.z = pack_bf16((a[4] + O) * iv, (a[5] + O) * iv);
        p.w = pack_bf16((a[6] + O) * iv, (a[7] + O) * iv);
        *((uint4*)(xs + st * XST + lx * 8)) = p;
    }
    __syncthreads();

    // ---- phase 2: MFMA y = x @ W^T ----
    {
        const int wave = t >> 6, lane = t & 63;
        int row_off, col_off;
        if constexpr (NT == 512) { row_off = (wave >> 2) * 16; col_off = (wave & 3) * 32; }
        else                     { row_off = 0;                col_off = wave * 32; }
        const int lm   = lane & 15;
        const int quad = lane >> 4;
        f32x4 acc[2] = {f32x4{0,0,0,0}, f32x4{0,0,0,0}};
        const ushort* xrow = xs + (row_off + lm) * XST + quad * 8;   // LDS
        const ushort* __restrict__ wrow = wb + (size_t)(col_off + lm) * DIM + quad * 8;
        #pragma unroll
        for (int kk = 0; kk < 4; ++kk) {
            const bf16x8 af = __builtin_bit_cast(bf16x8, *(const u32x4*)(xrow + kk * 32));
            #pragma unroll
            for (int c = 0; c < 2; ++c) {
                const bf16x8 bfr = __builtin_bit_cast(bf16x8,
                    *(const u32x4*)(wrow + (size_t)c * 16 * DIM + kk * 32));
                acc[c] = __builtin_amdgcn_mfma_f32_16x16x32_bf16(af, bfr, acc[c], 0, 0, 0);
            }
        }
        #pragma unroll
        for (int c = 0; c < 2; ++c) {
            #pragma unroll
            for (int r = 0; r < 4; ++r)
                ys[(row_off + quad * 4 + r) * RST + col_off + c * 16 + lm] = acc[c][r];
        }
    }
    __syncthreads();

    // ---- phase 3: LN + ELU; 16 threads per row; requant (or fp32 out) ----
    {
        const int r   = t >> 4;              // row 0..NRT-1
        const int seg = t & 15;              // 0..15
        const int db  = seg * 8;
        const float* yr = ys + r * RST + db;
        float vs[8];
        {
            const float4 y0 = ((const float4*)yr)[0];
            const float4 y1 = ((const float4*)yr)[1];
            const float4 b0 = ((const float4*)(bias + db))[0];
            const float4 b1 = ((const float4*)(bias + db))[1];
            vs[0] = y0.x + b0.x; vs[1] = y0.y + b0.y; vs[2] = y0.z + b0.z; vs[3] = y0.w + b0.w;
            vs[4] = y1.x + b1.x; vs[5] = y1.y + b1.y; vs[6] = y1.z + b1.z; vs[7] = y1.w + b1.w;
        }
        float s1 = 0.0f, s2 = 0.0f;
        #pragma unroll
        for (int i = 0; i < 8; ++i) { s1 += vs[i]; s2 += vs[i] * vs[i]; }
        #pragma unroll
        for (int m = 1; m < 16; m <<= 1) {
            s1 += __shfl_xor(s1, m);
            s2 += __shfl_xor(s2, m);
        }
        const float mu  = s1 * (1.0f / 128.0f);
        const float var = s2 * (1.0f / 128.0f) - mu * mu;
        const float rs  = rsqrtf(var + LN_EPS);
        float ov[8];
        {
            const float4 g0 = ((const float4*)(gamma + db))[0];
            const float4 g1 = ((const float4*)(gamma + db))[1];
            const float4 t0 = ((const float4*)(beta + db))[0];
            const float4 t1 = ((const float4*)(beta + db))[1];
            float z;
            z = (vs[0] - mu) * rs * g0.x + t0.x; ov[0] = (z > 0.0f) ? z : __expf(z) - 1.0f;
            z = (vs[1] - mu) * rs * g0.y + t0.y; ov[1] = (z > 0.0f) ? z : __expf(z) - 1.0f;
            z = (vs[2] - mu) * rs * g0.z + t0.z; ov[2] = (z > 0.0f) ? z : __expf(z) - 1.0f;
            z = (vs[3] - mu) * rs * g0.w + t0.w; ov[3] = (z > 0.0f) ? z : __expf(z) - 1.0f;
            z = (vs[4] - mu) * rs * g1.x + t1.x; ov[4] = (z > 0.0f) ? z : __expf(z) - 1.0f;
            z = (vs[5] - mu) * rs * g1.y + t1.y; ov[5] = (z > 0.0f) ? z : __expf(z) - 1.0f;
            z = (vs[6] - mu) * rs * g1.z + t1.z; ov[6] = (z > 0.0f) ? z : __expf(z) - 1.0f;
            z = (vs[7] - mu) * rs * g1.w + t1.w; ov[7] = (z > 0.0f) ? z : __expf(z) - 1.0f;
        }
        const int slot = rows + r;
        if (OUT_FP32) {
            if (slot < nrows) {
                float* op = fpout + (size_t)slot * DIM + db;
                ((float4*)op)[0] = make_float4(ov[0], ov[1], ov[2], ov[3]);
                ((float4*)op)[1] = make_float4(ov[4], ov[5], ov[6], ov[7]);
            }
        } else {
            float mn = ov[0], mx = ov[0];
            #pragma unroll
            for (int j = 1; j < 8; ++j) { mn = fminf(mn, ov[j]); mx = fmaxf(mx, ov[j]); }
            #pragma unroll
            for (int m = 1; m < 16; m <<= 1) {
                mn = fminf(mn, __shfl_xor(mn, m));
                mx = fmaxf(mx, __shfl_xor(mx, m));
            }
            if (slot < nrows) {
                const float rng = mx - mn;
                const float rcp = (rng > 0.0f) ? 255.0f / rng : 0.0f;
                uint bq[8];
                #pragma unroll
                for (int j = 0; j < 8; ++j)
                    bq[j] = (uint)fminf(255.0f, fmaf(ov[j] - mn, rcp, 0.5f));
                uint2 q;
                q.x = bq[0] | (bq[1] << 8) | (bq[2] << 16) | (bq[3] << 24);
                q.y = bq[4] | (bq[5] << 8) | (bq[6] << 16) | (bq[7] << 24);
                ((uint2*)(qout + (size_t)slot * DIM))[seg] = q;
                if (seg == 0) meta_out[slot] = make_float2(rng * (1.0f / 255.0f), mn);
            }
        }
    }
}

extern "C" void kernel_launch(void* const* d_in, const int* in_sizes, int n_in,
                              void* d_out, int out_size, void* d_ws, size_t ws_size,
                              hipStream_t stream) {
    const float* emb   = (const float*)d_in[0];
    const float* W     = (const float*)d_in[1];
    const float* bias  = (const float*)d_in[2];
    const float* gamma = (const float*)d_in[3];
    const float* beta  = (const float*)d_in[4];
    const int*   src   = (const int*)d_in[5];
    const int*   dst   = (const int*)d_in[6];
    const int*   uid   = (const int*)d_in[7];

    // workspace layout (~29 MB); Q buffers have an (unread-payload) pad row at index
    // N_NODES whose META is zero -> dequantizes to exact 0 (tail-clamp target)
    const size_t QSZ = (size_t)(N_NODES + 1) * DIM;   // bytes per int8 feature buffer
    uchar*  Q0  = (uchar*)d_ws;
    uchar*  Q1  = Q0 + QSZ;
    uchar*  Q2  = Q1 + QSZ;
    ushort* WB  = (ushort*)(Q2 + QSZ);                // 3*128*128 bf16
    float2* M0  = (float2*)(WB + 3 * DIM * DIM);      // MROW float2
    float2* M1  = M0 + MROW;
    float2* M2  = M1 + MROW;
    int*    off  = (int*)(M2 + MROW);                 // 50000 (+pad)
    int*    degv = off + (N_NODES + 4);               // 50000 (+pad)
    int*    bcur = degv + (N_NODES + 4);              // NBUCK (+pad)
    int*    pak  = bcur + (NBUCK + 2);                // NBUCK*BCAP packed (src<<6)|(dst&63)
    int*    csr  = pak + NBUCK * BCAP;                // NBUCK*BCAP + 16 overread pad

    prep_kernel<<<QBLK + WBLK + 1, 256, 0, stream>>>(emb, Q0, M0, W, WB, bcur, M1, M2);
    part_kernel<<<NCHUNK, 256, 0, stream>>>(src, dst, bcur, pak);
    bucket_kernel<<<NBUCK, 256, 0, stream>>>(pak, bcur, off, degv, csr);

    // layer 1: Q0 -> Q1 (r5-proven 512-thread config)
    layer_kernel<512, false><<<(N_NODES + 31) / 32, 512, 0, stream>>>(
        Q0, M0, Q1, M1, nullptr, off, degv, csr, nullptr, WB,
        bias, gamma, beta, N_NODES);
    // layer 2: Q1 -> Q2 (A/B: 256-thread / 16-node tiling, spill-safe bounds)
    layer_kernel<256, false><<<(N_NODES + 15) / 16, 256, 0, stream>>>(
        Q1, M1, Q2, M2, nullptr, off, degv, csr, nullptr, WB + DIM * DIM,
        bias + DIM, gamma + DIM, beta + DIM, N_NODES);
    // layer 3: uid nodes only, Q2 -> d_out (fp32, no requant)
    layer_kernel<512, true><<<N_UID / 32, 512, 0, stream>>>(
        Q2, M2, nullptr, nullptr, (float*)d_out, off, degv, csr, uid,
        WB + 2 * DIM * DIM, bias + 2 * DIM, gamma + 2 * DIM, beta + 2 * DIM, N_UID);
}